// Round 6
// baseline (1018.743 us; speedup 1.0000x reference)
//
#include <hip/hip_runtime.h>
#include <math.h>

// Shapes: B=8, N=1024, D=64, H=4, DH=16, DI=128, DS=64, DTR=4, MAXP=512

__device__ __forceinline__ float wsum64(float v){
#pragma unroll
  for(int m=32;m>0;m>>=1) v += __shfl_xor(v, m, 64);
  return v;
}
__device__ __forceinline__ float wmax64(float v){
#pragma unroll
  for(int m=32;m>0;m>>=1) v = fmaxf(v, __shfl_xor(v, m, 64));
  return v;
}
__device__ __forceinline__ float silu_f(float x){ return x / (1.f + __expf(-x)); }

// ---------------------------------------------------------------------------
// K0a: transpose rel_emb -> relT[c][dist] (dist stride-1).
__global__ __launch_bounds__(256) void k_relT(
    const float* __restrict__ rel, float* __restrict__ relT){
  int idx = blockIdx.x*256 + threadIdx.x;   // over 16*1025
  if (idx < 16*1025){
    int c = idx / 1025;
    int d = idx - c*1025;
    relT[idx] = rel[d*16 + c];
  }
}

// K0b: transpose c1_w[i][cc][k] -> c1wT[(cc*4+k)*512 + i] (i stride-1).
__global__ __launch_bounds__(256) void k_c1wT(
    const float* __restrict__ c1w, float* __restrict__ c1wT){
  int idx = blockIdx.x*256 + threadIdx.x;   // over 512*64*4 = 131072
  int row = idx >> 9;          // cc*4+k
  int i   = idx & 511;
  c1wT[idx] = c1w[(size_t)i*256 + row];
}

// ---------------------------------------------------------------------------
// K1: LN1 + Q / KV projection.  wave per token. K,V stored D-MAJOR.
__global__ __launch_bounds__(256) void k_ln1_qkv(
    const float* __restrict__ x, const float* __restrict__ w1, const float* __restrict__ b1,
    const float* __restrict__ Wq, const float* __restrict__ Wkv,
    float* __restrict__ qb, float* __restrict__ kbT, float* __restrict__ vbT){
  int lane = threadIdx.x & 63, warp = threadIdx.x >> 6;
  int token = blockIdx.x*4 + warp;            // 0..8191
  __shared__ float xt[4][64];
  float xv = x[(size_t)token*64 + lane];
  float mean = wsum64(xv) * 0.015625f;
  float dlt = xv - mean;
  float var = wsum64(dlt*dlt) * 0.015625f;
  float xn = dlt * rsqrtf(var + 1e-5f) * w1[lane] + b1[lane];
  xt[warp][lane] = xn;
  __syncthreads();
  float aq=0.f, ak=0.f, av=0.f;
#pragma unroll 4
  for(int dd=0; dd<64; ++dd){
    float xd = xt[warp][dd];
    aq += xd * Wq[dd*64 + lane];
    ak += xd * Wkv[dd*128 + lane];
    av += xd * Wkv[dd*128 + 64 + lane];
  }
  int b = token >> 10, i = token & 1023;
  int h = lane >> 4, dh = lane & 15;
  size_t o  = (((size_t)(b*4 + h))*1024 + i)*16 + dh;   // (B,H,N,DH) for q
  size_t oT = (((size_t)(b*4 + h))*16 + dh)*1024 + i;   // (B,H,DH,N) for k,v
  qb[o]=aq; kbT[oT]=ak; vbT[oT]=av;
}

// ---------------------------------------------------------------------------
// K2: attention. ONE query row per wave; per-lane online softmax; all hot
// loads lane-contiguous. launch_bounds(256,8): VGPR cap 64 (52 used) ->
// ~8 waves/SIMD to hide the unroll-1 load latency.
__global__ __launch_bounds__(256, 8) void k_attn(
    const float* __restrict__ qb, const float* __restrict__ kbT, const float* __restrict__ vbT,
    const int* __restrict__ dmask, const float* __restrict__ relT,
    float* __restrict__ attn_raw){
  int tid = threadIdx.x;
  int lane = tid & 63, wv = tid >> 6;       // wave 0..3
  int bh  = blockIdx.y;                     // 0..31
  int i   = blockIdx.x*4 + wv;              // query row, grid.x = 256
  int b = bh >> 2, h = bh & 3;

  float q[16];
  {
    const float4* qp = (const float4*)(qb + ((size_t)bh*1024 + i)*16);
    float4 q0=qp[0], q1=qp[1], q2=qp[2], q3=qp[3];
    q[ 0]=q0.x*0.25f; q[ 1]=q0.y*0.25f; q[ 2]=q0.z*0.25f; q[ 3]=q0.w*0.25f;
    q[ 4]=q1.x*0.25f; q[ 5]=q1.y*0.25f; q[ 6]=q1.z*0.25f; q[ 7]=q1.w*0.25f;
    q[ 8]=q2.x*0.25f; q[ 9]=q2.y*0.25f; q[10]=q2.z*0.25f; q[11]=q2.w*0.25f;
    q[12]=q3.x*0.25f; q[13]=q3.y*0.25f; q[14]=q3.z*0.25f; q[15]=q3.w*0.25f;
  }
  const float* kb = kbT + (size_t)bh*16*1024;
  const float* vb = vbT + (size_t)bh*16*1024;
  const int* mbase = dmask + ((size_t)bh*1024 + i)*1024;

  float m = -3.0e38f, sum = 0.f;
  float a[16];
#pragma unroll
  for(int c=0;c<16;++c) a[c]=0.f;

#pragma unroll 1
  for(int t=0;t<16;++t){
    int j = lane + 64*t;
    int mk = mbase[j];
    int d0 = i - j; d0 = d0 < -512 ? -512 : (d0 > 512 ? 512 : d0); d0 += 512;
    float sv = 0.f;
#pragma unroll
    for(int c=0;c<16;++c) sv += q[c]*(kb[c*1024 + j] + relT[c*1025 + d0]);
    sv += mk ? -1.0e12f : 0.0f;
    float mn = fmaxf(m, sv);
    float alpha = __expf(m - mn);
    float p = __expf(sv - mn);
    m = mn;
    sum = sum*alpha + p;
#pragma unroll
    for(int c=0;c<16;++c) a[c] = a[c]*alpha + p*vb[c*1024 + j];
  }
  // merge lanes: rescale to the global row max, then reduce
  float M = wmax64(m);
  float sc = __expf(m - M);
  sum = wsum64(sum*sc);
#pragma unroll
  for(int c=0;c<16;++c){
    float ac = a[c]*sc;
    ac += __shfl_xor(ac, 32, 64);
    ac += __shfl_xor(ac, 16, 64);
    a[c] = ac;
  }
  __shared__ float red[4][16][17];
  __shared__ float sums[4];
  if (lane < 16){
#pragma unroll
    for(int c=0;c<16;++c) red[wv][lane][c] = a[c];
  }
  if (lane == 0) sums[wv] = sum;
  __syncthreads();
  if (tid < 64){
    int row = tid >> 4, c = tid & 15;
    float tot = 0.f;
#pragma unroll
    for(int g=0; g<16; ++g) tot += red[row][g][c];
    int irow = blockIdx.x*4 + row;
    attn_raw[((size_t)b*1024 + irow)*64 + h*16 + c] = tot / sums[row];
  }
}

// ---------------------------------------------------------------------------
// K3: Wo proj + double residual + LN2 + W_in (u0, silu(z)). wave per token.
__global__ __launch_bounds__(256) void k_post_attn(
    const float* __restrict__ x, const float* __restrict__ attn_raw,
    const float* __restrict__ Wo, const float* __restrict__ bo,
    const float* __restrict__ ln2w, const float* __restrict__ ln2b,
    const float* __restrict__ W_in,
    float* __restrict__ x2, float* __restrict__ u0, float* __restrict__ zsarr){
  int lane = threadIdx.x & 63, warp = threadIdx.x >> 6;
  int token = blockIdx.x*4 + warp;
  __shared__ float ar[4][64];
  __shared__ float lnv[4][64];
  ar[warp][lane] = attn_raw[(size_t)token*64 + lane];
  __syncthreads();
  float acc = bo[lane];
#pragma unroll 4
  for(int dd=0;dd<64;++dd) acc += ar[warp][dd]*Wo[dd*64+lane];
  float t = 2.f*x[(size_t)token*64+lane] + acc;    // x + (attn_out + x)
  x2[(size_t)token*64+lane] = t;
  float mean = wsum64(t)*0.015625f;
  float dlt = t-mean;
  float var = wsum64(dlt*dlt)*0.015625f;
  float ln = dlt*rsqrtf(var+1e-5f)*ln2w[lane]+ln2b[lane];
  lnv[warp][lane]=ln;
  __syncthreads();
  float a0=0.f,a1=0.f,a2=0.f,a3=0.f;
#pragma unroll 4
  for(int dd=0;dd<64;++dd){
    float xd = lnv[warp][dd];
    const float* wr = W_in + dd*256;
    a0 += xd*wr[lane]; a1 += xd*wr[lane+64]; a2 += xd*wr[lane+128]; a3 += xd*wr[lane+192];
  }
  u0[(size_t)token*128 + lane] = a0;
  u0[(size_t)token*128 + 64 + lane] = a1;
  zsarr[(size_t)token*128 + lane] = silu_f(a2);
  zsarr[(size_t)token*128 + 64 + lane] = silu_f(a3);
}

// ---------------------------------------------------------------------------
// K4: causal depthwise conv4 + silu + x-proj(132) + softplus dt. 128 lanes/token.
__global__ __launch_bounds__(256) void k_conv_proj(
    const float* __restrict__ u0, const float* __restrict__ conv_w, const float* __restrict__ conv_b,
    const float* __restrict__ W_xproj, const float* __restrict__ W_dt, const float* __restrict__ b_dt,
    float* __restrict__ uarr, float* __restrict__ Bmp, float* __restrict__ Cmp, float* __restrict__ dtarr){
  int sub = threadIdx.x >> 7, c = threadIdx.x & 127;
  int token = blockIdx.x*2 + sub;
  int b = token >> 10, i = token & 1023;
  __shared__ float us[2][128];
  __shared__ float dtin[2][4];
  float acc = conv_b[c];
#pragma unroll
  for(int k2=0;k2<4;++k2){
    int t2 = i - 3 + k2;
    if (t2 >= 0) acc += u0[((size_t)b*1024 + t2)*128 + c]*conv_w[c*4+k2];
  }
  float uv = silu_f(acc);
  uarr[(size_t)token*128 + c] = uv;
  us[sub][c] = uv;
  __syncthreads();
  float accA = 0.f, accB = 0.f;
  int cB = 128 + (c & 3);
#pragma unroll 4
  for(int dd=0; dd<128; ++dd){
    float xd = us[sub][dd];
    accA += xd * W_xproj[dd*132 + c];
    accB += xd * W_xproj[dd*132 + cB];
  }
  if (c < 4){ dtin[sub][c] = accA; Cmp[(size_t)token*64 + 60 + c] = accB; }
  else if (c < 68) Bmp[(size_t)token*64 + (c-4)] = accA;
  else             Cmp[(size_t)token*64 + (c-68)] = accA;
  __syncthreads();
  float dv = b_dt[c];
#pragma unroll
  for(int r2=0;r2<4;++r2) dv += dtin[sub][r2]*W_dt[r2*128 + c];
  dv = fmaxf(dv, 0.f) + log1pf(expf(-fabsf(dv)));   // softplus, stable
  dtarr[(size_t)token*128 + c] = dv;
}

// ---------------------------------------------------------------------------
// K5: selective scan. wave = (b,d), lane = s. Batch 8 recurrence steps, then
// 8 independent wave reductions (ILP hides shuffle latency).
__global__ __launch_bounds__(256) void k_scan(
    const float* __restrict__ dtarr, const float* __restrict__ uarr,
    const float* __restrict__ Bmp, const float* __restrict__ Cmp,
    const float* __restrict__ zsarr, const float* __restrict__ A_log,
    const float* __restrict__ Dm, float* __restrict__ ymp){
  int lane = threadIdx.x & 63, warp = threadIdx.x >> 6;
  int g = blockIdx.x*4 + warp;          // 0..1023
  int b = g >> 7, d = g & 127;
  float A = -expf(A_log[d*64 + lane]);
  float Dv = Dm[d];
  const float* dtp = dtarr + (size_t)b*1024*128 + d;
  const float* up  = uarr  + (size_t)b*1024*128 + d;
  const float* zp  = zsarr + (size_t)b*1024*128 + d;
  const float* Bp  = Bmp   + (size_t)b*1024*64 + lane;
  const float* Cp  = Cmp   + (size_t)b*1024*64 + lane;
  float* yp        = ymp   + (size_t)b*1024*128 + d;
  float h = 0.f;
  for(int t0=0; t0<1024; t0+=8){
    float dtc[8], uc[8], Bc[8], Cc[8], zc[8];
#pragma unroll
    for(int r=0;r<8;++r){
      dtc[r]=dtp[(size_t)(t0+r)*128]; uc[r]=up[(size_t)(t0+r)*128];
      Bc[r]=Bp[(size_t)(t0+r)*64];    Cc[r]=Cp[(size_t)(t0+r)*64];
      zc[r]=zp[(size_t)(t0+r)*128];
    }
    float hc[8];
#pragma unroll
    for(int r=0;r<8;++r){
      float dt = dtc[r];
      h = h*__expf(dt*A) + dt*uc[r]*Bc[r];
      hc[r] = h*Cc[r];
    }
    float y[8];
#pragma unroll
    for(int r=0;r<8;++r) y[r] = wsum64(hc[r]);
    if (lane==0){
#pragma unroll
      for(int r=0;r<8;++r) yp[(size_t)(t0+r)*128] = (y[r] + uc[r]*Dv)*zc[r];
    }
  }
}

// ---------------------------------------------------------------------------
// K6: y @ W_out + leaky + group(4)-RMS-norm. wave per token.
__global__ __launch_bounds__(256) void k_wout(
    const float* __restrict__ ymp, const float* __restrict__ W_out,
    const float* __restrict__ gamma, float* __restrict__ marr){
  int lane = threadIdx.x & 63, warp = threadIdx.x >> 6;
  int token = blockIdx.x*4 + warp;
  __shared__ float ys[4][128];
  ys[warp][lane]      = ymp[(size_t)token*128 + lane];
  ys[warp][lane+64]   = ymp[(size_t)token*128 + 64 + lane];
  __syncthreads();
  float acc = 0.f;
#pragma unroll 4
  for(int dd=0; dd<128; ++dd) acc += ys[warp][dd]*W_out[dd*64 + lane];
  acc = acc >= 0.f ? acc : 0.01f*acc;                 // leaky relu
  float ss = acc*acc;
#pragma unroll
  for(int m=1;m<16;m<<=1) ss += __shfl_xor(ss, m, 64); // 16-lane group sum
  float rms = sqrtf(ss)*0.25f;                         // * dpg^-0.5 (dpg=16)
  marr[(size_t)token*64 + lane] = acc/(rms + 1e-5f)*gamma[lane];
}

// ---------------------------------------------------------------------------
// K7: GLU conv1 -> h2[b, tau(0..1026), i(0..255)], tau-major. Weights read
// from c1wT (lane-contiguous dwords).
__global__ __launch_bounds__(256) void k_h2(
    const float* __restrict__ marr, const float* __restrict__ c1wT,
    const float* __restrict__ c1b, float* __restrict__ h2){
  int b = blockIdx.y;
  int t0 = blockIdx.x * 16;
  int tid = threadIdx.x;
  __shared__ float ms[19][64];
  for(int l = tid; l < 19*64; l += 256){
    int row = l >> 6, cc = l & 63;
    int t = t0 - 3 + row;
    ms[row][cc] = (t >= 0 && t < 1024) ? marr[((size_t)b*1024 + t)*64 + cc] : 0.f;
  }
  __syncthreads();
  int i = tid;
  float acc1[16], acc2[16];
#pragma unroll
  for(int tl=0;tl<16;++tl){ acc1[tl]=0.f; acc2[tl]=0.f; }
  for(int cc=0; cc<64; ++cc){
    float mv[19];
#pragma unroll
    for(int r2=0;r2<19;++r2) mv[r2] = ms[r2][cc];
    const float* wr = c1wT + (size_t)cc*4*512;
    float wa0 = wr[      i], wa1 = wr[ 512+i], wa2 = wr[1024+i], wa3 = wr[1536+i];
    float wg0 = wr[  256+i], wg1 = wr[ 768+i], wg2 = wr[1280+i], wg3 = wr[1792+i];
#pragma unroll
    for(int tl=0; tl<16; ++tl){
      acc1[tl] += wa0*mv[tl+0] + wa1*mv[tl+1] + wa2*mv[tl+2] + wa3*mv[tl+3];
      acc2[tl] += wg0*mv[tl+0] + wg1*mv[tl+1] + wg2*mv[tl+2] + wg3*mv[tl+3];
    }
  }
  float bb1 = c1b[i], bb2 = c1b[i+256];
#pragma unroll
  for(int tl=0; tl<16; ++tl){
    int t = t0 + tl;
    if (t < 1027){
      float o1 = acc1[tl] + bb1;
      float o2 = acc2[tl] + bb2;
      h2[((size_t)b*1027 + t)*256 + i] = o1 * silu_f(o2);
    }
  }
}

// ---------------------------------------------------------------------------
// K8: conv2 (flipped d1_w) + 0.5*ff + residuals + LN3 -> out.
// 16 tokens per block: d1w streamed ONCE per block (256KB), traffic cut 4x.
__global__ __launch_bounds__(256) void k_ff_final(
    const float* __restrict__ h2, const float* __restrict__ d1w, const float* __restrict__ d1b,
    const float* __restrict__ x2, const float* __restrict__ marr,
    const float* __restrict__ ln3w, const float* __restrict__ ln3b,
    float* __restrict__ out){
  int b = blockIdx.y;
  int s0 = blockIdx.x * 16;      // grid.x = 64
  int tid = threadIdx.x;
  int o = tid & 63, sg = tid >> 6;
  __shared__ float hs[19][256];
  for(int l = tid; l < 19*256; l += 256){
    int row = l >> 8, cc = l & 255;
    hs[row][cc] = h2[((size_t)b*1027 + s0 + row)*256 + cc];
  }
  __syncthreads();
  int sl = sg*4;
  float acc0=0.f, acc1=0.f, acc2=0.f, acc3=0.f;
  const float4* wb = (const float4*)d1w + o;   // d1w[i][o][0..3], lane-contig
#pragma unroll 2
  for(int i2=0; i2<256; ++i2){
    float4 wv = wb[(size_t)i2*64];
    float h0=hs[sl+0][i2], h1=hs[sl+1][i2], h2v=hs[sl+2][i2], h3=hs[sl+3][i2];
    float h4=hs[sl+4][i2], h5=hs[sl+5][i2], h6=hs[sl+6][i2];
    acc0 += h0*wv.w + h1*wv.z + h2v*wv.y + h3*wv.x;
    acc1 += h1*wv.w + h2v*wv.z + h3*wv.y + h4*wv.x;
    acc2 += h2v*wv.w + h3*wv.z + h4*wv.y + h5*wv.x;
    acc3 += h3*wv.w + h4*wv.z + h5*wv.y + h6*wv.x;
  }
  float accs[4] = {acc0, acc1, acc2, acc3};
  float bo_ = d1b[o];
#pragma unroll
  for(int r=0;r<4;++r){
    int s = s0 + sl + r;
    size_t idx = ((size_t)b*1024 + s)*64 + o;
    float tot = x2[idx] + marr[idx] + 0.5f*(accs[r] + bo_);
    float mean = wsum64(tot)*0.015625f;
    float dlt = tot - mean;
    float var = wsum64(dlt*dlt)*0.015625f;
    out[idx] = dlt*rsqrtf(var+1e-5f)*ln3w[o] + ln3b[o];
  }
}

// ---------------------------------------------------------------------------
extern "C" void kernel_launch(void* const* d_in, const int* in_sizes, int n_in,
                              void* d_out, int out_size, void* d_ws, size_t ws_size,
                              hipStream_t stream){
  const float* x       = (const float*)d_in[0];
  const int*   dmask   = (const int*)  d_in[1];   // bool -> int32 per harness
  const float* ln1w    = (const float*)d_in[2];
  const float* ln1b    = (const float*)d_in[3];
  const float* Wq      = (const float*)d_in[4];
  const float* Wkv     = (const float*)d_in[5];
  const float* Wo      = (const float*)d_in[6];
  const float* bo      = (const float*)d_in[7];
  const float* rel     = (const float*)d_in[8];
  const float* ln2w    = (const float*)d_in[9];
  const float* ln2b    = (const float*)d_in[10];
  const float* W_in    = (const float*)d_in[11];
  const float* conv_w  = (const float*)d_in[12];
  const float* conv_b  = (const float*)d_in[13];
  const float* W_xproj = (const float*)d_in[14];
  const float* W_dt    = (const float*)d_in[15];
  const float* b_dt    = (const float*)d_in[16];
  const float* A_log   = (const float*)d_in[17];
  const float* Dm      = (const float*)d_in[18];
  const float* W_out   = (const float*)d_in[19];
  const float* gamma   = (const float*)d_in[20];
  const float* c1w     = (const float*)d_in[21];
  const float* c1b     = (const float*)d_in[22];
  const float* d1w     = (const float*)d_in[23];
  const float* d1b     = (const float*)d_in[24];
  const float* ln3w    = (const float*)d_in[25];
  const float* ln3b    = (const float*)d_in[26];
  float* outp = (float*)d_out;

  float* ws = (float*)d_ws;
  float* qb       = ws;              // 524288
  float* kbT      = qb      + 524288;
  float* vbT      = kbT     + 524288;
  float* attn_raw = vbT     + 524288;
  float* x2       = attn_raw+ 524288;
  float* u0       = x2      + 524288;   // 1048576
  float* zsarr    = u0      + 1048576;
  float* uarr     = zsarr   + 1048576;
  float* dtarr    = uarr    + 1048576;
  float* Bmp      = dtarr   + 1048576;  // 524288
  float* Cmp      = Bmp     + 524288;
  float* ymp      = Cmp     + 524288;   // 1048576
  float* marr     = ymp     + 1048576;  // 524288
  float* h2       = marr    + 524288;   // 8*1027*256 = 2103296
  float* relT     = h2      + 2103296;  // 16*1025 = 16400
  float* c1wT     = relT    + 16400;    // 512*64*4 = 131072

  k_relT     <<<65, 256, 0, stream>>>(rel, relT);
  k_c1wT     <<<512, 256, 0, stream>>>(c1w, c1wT);
  k_ln1_qkv  <<<2048, 256, 0, stream>>>(x, ln1w, ln1b, Wq, Wkv, qb, kbT, vbT);
  k_attn     <<<dim3(256,32), 256, 0, stream>>>(qb, kbT, vbT, dmask, relT, attn_raw);
  k_post_attn<<<2048, 256, 0, stream>>>(x, attn_raw, Wo, bo, ln2w, ln2b, W_in, x2, u0, zsarr);
  k_conv_proj<<<4096, 256, 0, stream>>>(u0, conv_w, conv_b, W_xproj, W_dt, b_dt, uarr, Bmp, Cmp, dtarr);
  k_scan     <<<256, 256, 0, stream>>>(dtarr, uarr, Bmp, Cmp, zsarr, A_log, Dm, ymp);
  k_wout     <<<2048, 256, 0, stream>>>(ymp, W_out, gamma, marr);
  k_h2       <<<dim3(65,8), 256, 0, stream>>>(marr, c1wT, c1b, h2);
  k_ff_final <<<dim3(64,8), 256, 0, stream>>>(h2, d1w, d1b, x2, marr, ln3w, ln3b, outp);
}

// Round 7
// 813.181 us; speedup vs baseline: 1.2528x; 1.2528x over previous
//
#include <hip/hip_runtime.h>
#include <math.h>

// Shapes: B=8, N=1024, D=64, H=4, DH=16, DI=128, DS=64, DTR=4, MAXP=512

__device__ __forceinline__ float wsum64(float v){
#pragma unroll
  for(int m=32;m>0;m>>=1) v += __shfl_xor(v, m, 64);
  return v;
}
__device__ __forceinline__ float wmax64(float v){
#pragma unroll
  for(int m=32;m>0;m>>=1) v = fmaxf(v, __shfl_xor(v, m, 64));
  return v;
}
__device__ __forceinline__ float silu_f(float x){ return x / (1.f + __expf(-x)); }
__device__ __forceinline__ int clip512(int d){ return d < -512 ? -512 : (d > 512 ? 512 : d); }

// ---------------------------------------------------------------------------
// K0a: transpose rel_emb -> relT[c][dist] (dist stride-1).
__global__ __launch_bounds__(256) void k_relT(
    const float* __restrict__ rel, float* __restrict__ relT){
  int idx = blockIdx.x*256 + threadIdx.x;   // over 16*1025
  if (idx < 16*1025){
    int c = idx / 1025;
    int d = idx - c*1025;
    relT[idx] = rel[d*16 + c];
  }
}

// K0b: transpose c1_w[i][cc][k] -> c1wT[(cc*4+k)*512 + i] (i stride-1).
__global__ __launch_bounds__(256) void k_c1wT(
    const float* __restrict__ c1w, float* __restrict__ c1wT){
  int idx = blockIdx.x*256 + threadIdx.x;   // over 512*64*4 = 131072
  int row = idx >> 9;          // cc*4+k
  int i   = idx & 511;
  c1wT[idx] = c1w[(size_t)i*256 + row];
}

// ---------------------------------------------------------------------------
// K1: LN1 + Q / KV projection.  wave per token. K,V stored D-MAJOR.
__global__ __launch_bounds__(256) void k_ln1_qkv(
    const float* __restrict__ x, const float* __restrict__ w1, const float* __restrict__ b1,
    const float* __restrict__ Wq, const float* __restrict__ Wkv,
    float* __restrict__ qb, float* __restrict__ kbT, float* __restrict__ vbT){
  int lane = threadIdx.x & 63, warp = threadIdx.x >> 6;
  int token = blockIdx.x*4 + warp;            // 0..8191
  __shared__ float xt[4][64];
  float xv = x[(size_t)token*64 + lane];
  float mean = wsum64(xv) * 0.015625f;
  float dlt = xv - mean;
  float var = wsum64(dlt*dlt) * 0.015625f;
  float xn = dlt * rsqrtf(var + 1e-5f) * w1[lane] + b1[lane];
  xt[warp][lane] = xn;
  __syncthreads();
  float aq=0.f, ak=0.f, av=0.f;
#pragma unroll 4
  for(int dd=0; dd<64; ++dd){
    float xd = xt[warp][dd];
    aq += xd * Wq[dd*64 + lane];
    ak += xd * Wkv[dd*128 + lane];
    av += xd * Wkv[dd*128 + 64 + lane];
  }
  int b = token >> 10, i = token & 1023;
  int h = lane >> 4, dh = lane & 15;
  size_t o  = (((size_t)(b*4 + h))*1024 + i)*16 + dh;   // (B,H,N,DH) for q
  size_t oT = (((size_t)(b*4 + h))*16 + dh)*1024 + i;   // (B,H,DH,N) for k,v
  qb[o]=aq; kbT[oT]=ak; vbT[oT]=av;
}

// ---------------------------------------------------------------------------
// K2: attention. Block = 4 waves = 8 query rows (2 rows/wave). Per j-chunk of
// 64: (a) stage the ~71-wide rel window in LDS, (b) cooperatively compute
// Gc[r][jj] = q_r . rel[dist], (c) QK+online-softmax+PV with K/V loaded once
// per 2 rows. Per-elem L1 traffic: 196B -> ~77B.
__global__ __launch_bounds__(256, 4) void k_attn(
    const float* __restrict__ qb, const float* __restrict__ kbT, const float* __restrict__ vbT,
    const int* __restrict__ dmask, const float* __restrict__ relT,
    float* __restrict__ attn_raw){
  int tid = threadIdx.x;
  int lane = tid & 63, wv = tid >> 6;       // wave 0..3
  int bh  = blockIdx.y;                     // 0..31
  int i0  = blockIdx.x*8;                   // grid.x = 128
  int b = bh >> 2, h = bh & 3;
  int r0 = wv*2, r1 = wv*2 + 1;
  int i_a = i0 + r0, i_b = i0 + r1;

  __shared__ float qs[8][16];        // scaled q rows
  __shared__ float relS[16][80];     // rel window for current chunk
  __shared__ float Gc[8][64];        // per-(row, j-offset) rel dot
  __shared__ float red[8][16][17];
  __shared__ float sums[8];

  if (tid < 128){
    int r = tid >> 4, c = tid & 15;
    qs[r][c] = qb[((size_t)bh*1024 + i0 + r)*16 + c] * 0.25f;
  }
  __syncthreads();
  float q0[16], q1[16];
#pragma unroll
  for(int c=0;c<16;++c){ q0[c]=qs[r0][c]; q1[c]=qs[r1][c]; }

  const float* kb = kbT + (size_t)bh*16*1024;
  const float* vb = vbT + (size_t)bh*16*1024;
  const int* mb0 = dmask + ((size_t)bh*1024 + i_a)*1024;
  const int* mb1 = dmask + ((size_t)bh*1024 + i_b)*1024;

  float m0=-3.0e38f, m1=-3.0e38f, s0=0.f, s1=0.f;
  float a0[16], a1[16];
#pragma unroll
  for(int c=0;c<16;++c){ a0[c]=0.f; a1[c]=0.f; }

#pragma unroll 1
  for(int t=0;t<16;++t){
    int j0 = 64*t;
    int dlo = clip512(i0 - j0 - 63) + 512;      // block-uniform window base
    // --- stage rel window (1280 dwords, 5 per thread) ---
#pragma unroll
    for(int e0=0;e0<5;++e0){
      int e = tid + 256*e0;
      int c = e / 80, dd = e - c*80;
      int d = dlo + dd; d = d > 1024 ? 1024 : d;
      relS[c][dd] = relT[c*1025 + d];
    }
    __syncthreads();
    // --- compute Gc (512 entries, 2 per thread) ---
#pragma unroll
    for(int p=0;p<2;++p){
      int e = tid + 256*p;
      int r = e >> 6, jj = e & 63;
      int dd = clip512(i0 + r - j0 - jj) + 512 - dlo;
      float g = 0.f;
#pragma unroll
      for(int c=0;c<16;++c) g += qs[r][c]*relS[c][dd];
      Gc[r][jj] = g;
    }
    __syncthreads();
    // --- QK + online softmax + PV, 2 rows sharing K/V ---
    int j = j0 + lane;
    float kk[16];
#pragma unroll
    for(int c=0;c<16;++c) kk[c] = kb[c*1024 + j];
    float sv0 = Gc[r0][lane] + (mb0[j] ? -1.0e12f : 0.0f);
    float sv1 = Gc[r1][lane] + (mb1[j] ? -1.0e12f : 0.0f);
#pragma unroll
    for(int c=0;c<16;++c){ sv0 += q0[c]*kk[c]; sv1 += q1[c]*kk[c]; }
    float vv[16];
#pragma unroll
    for(int c=0;c<16;++c) vv[c] = vb[c*1024 + j];
    float mn0 = fmaxf(m0, sv0);
    float al0 = __expf(m0 - mn0);
    float p0  = __expf(sv0 - mn0);
    m0 = mn0; s0 = s0*al0 + p0;
#pragma unroll
    for(int c=0;c<16;++c) a0[c] = a0[c]*al0 + p0*vv[c];
    float mn1 = fmaxf(m1, sv1);
    float al1 = __expf(m1 - mn1);
    float p1  = __expf(sv1 - mn1);
    m1 = mn1; s1 = s1*al1 + p1;
#pragma unroll
    for(int c=0;c<16;++c) a1[c] = a1[c]*al1 + p1*vv[c];
  }
  // merge lanes per row
  float M0 = wmax64(m0), M1 = wmax64(m1);
  float sc0 = __expf(m0 - M0), sc1 = __expf(m1 - M1);
  s0 = wsum64(s0*sc0); s1 = wsum64(s1*sc1);
#pragma unroll
  for(int c=0;c<16;++c){
    float x0 = a0[c]*sc0;
    x0 += __shfl_xor(x0, 32, 64); x0 += __shfl_xor(x0, 16, 64);
    a0[c] = x0;
    float x1 = a1[c]*sc1;
    x1 += __shfl_xor(x1, 32, 64); x1 += __shfl_xor(x1, 16, 64);
    a1[c] = x1;
  }
  __syncthreads();   // protect Gc/relS reuse vs red (distinct arrays, but order waves)
  if (lane < 16){
#pragma unroll
    for(int c=0;c<16;++c){ red[r0][lane][c] = a0[c]; red[r1][lane][c] = a1[c]; }
  }
  if (lane == 0){ sums[r0] = s0; sums[r1] = s1; }
  __syncthreads();
  if (tid < 128){
    int row = tid >> 4, c = tid & 15;
    float tot = 0.f;
#pragma unroll
    for(int g=0; g<16; ++g) tot += red[row][g][c];
    int irow = i0 + row;
    attn_raw[((size_t)b*1024 + irow)*64 + h*16 + c] = tot / sums[row];
  }
}

// ---------------------------------------------------------------------------
// K3: Wo proj + double residual + LN2 + W_in (u0, silu(z)). wave per token.
__global__ __launch_bounds__(256) void k_post_attn(
    const float* __restrict__ x, const float* __restrict__ attn_raw,
    const float* __restrict__ Wo, const float* __restrict__ bo,
    const float* __restrict__ ln2w, const float* __restrict__ ln2b,
    const float* __restrict__ W_in,
    float* __restrict__ x2, float* __restrict__ u0, float* __restrict__ zsarr){
  int lane = threadIdx.x & 63, warp = threadIdx.x >> 6;
  int token = blockIdx.x*4 + warp;
  __shared__ float ar[4][64];
  __shared__ float lnv[4][64];
  ar[warp][lane] = attn_raw[(size_t)token*64 + lane];
  __syncthreads();
  float acc = bo[lane];
#pragma unroll 4
  for(int dd=0;dd<64;++dd) acc += ar[warp][dd]*Wo[dd*64+lane];
  float t = 2.f*x[(size_t)token*64+lane] + acc;    // x + (attn_out + x)
  x2[(size_t)token*64+lane] = t;
  float mean = wsum64(t)*0.015625f;
  float dlt = t-mean;
  float var = wsum64(dlt*dlt)*0.015625f;
  float ln = dlt*rsqrtf(var+1e-5f)*ln2w[lane]+ln2b[lane];
  lnv[warp][lane]=ln;
  __syncthreads();
  float a0=0.f,a1=0.f,a2=0.f,a3=0.f;
#pragma unroll 4
  for(int dd=0;dd<64;++dd){
    float xd = lnv[warp][dd];
    const float* wr = W_in + dd*256;
    a0 += xd*wr[lane]; a1 += xd*wr[lane+64]; a2 += xd*wr[lane+128]; a3 += xd*wr[lane+192];
  }
  u0[(size_t)token*128 + lane] = a0;
  u0[(size_t)token*128 + 64 + lane] = a1;
  zsarr[(size_t)token*128 + lane] = silu_f(a2);
  zsarr[(size_t)token*128 + 64 + lane] = silu_f(a3);
}

// ---------------------------------------------------------------------------
// K4: causal depthwise conv4 + silu + x-proj(132) + softplus dt. 128 lanes/token.
__global__ __launch_bounds__(256) void k_conv_proj(
    const float* __restrict__ u0, const float* __restrict__ conv_w, const float* __restrict__ conv_b,
    const float* __restrict__ W_xproj, const float* __restrict__ W_dt, const float* __restrict__ b_dt,
    float* __restrict__ uarr, float* __restrict__ Bmp, float* __restrict__ Cmp, float* __restrict__ dtarr){
  int sub = threadIdx.x >> 7, c = threadIdx.x & 127;
  int token = blockIdx.x*2 + sub;
  int b = token >> 10, i = token & 1023;
  __shared__ float us[2][128];
  __shared__ float dtin[2][4];
  float acc = conv_b[c];
#pragma unroll
  for(int k2=0;k2<4;++k2){
    int t2 = i - 3 + k2;
    if (t2 >= 0) acc += u0[((size_t)b*1024 + t2)*128 + c]*conv_w[c*4+k2];
  }
  float uv = silu_f(acc);
  uarr[(size_t)token*128 + c] = uv;
  us[sub][c] = uv;
  __syncthreads();
  float accA = 0.f, accB = 0.f;
  int cB = 128 + (c & 3);
#pragma unroll 4
  for(int dd=0; dd<128; ++dd){
    float xd = us[sub][dd];
    accA += xd * W_xproj[dd*132 + c];
    accB += xd * W_xproj[dd*132 + cB];
  }
  if (c < 4){ dtin[sub][c] = accA; Cmp[(size_t)token*64 + 60 + c] = accB; }
  else if (c < 68) Bmp[(size_t)token*64 + (c-4)] = accA;
  else             Cmp[(size_t)token*64 + (c-68)] = accA;
  __syncthreads();
  float dv = b_dt[c];
#pragma unroll
  for(int r2=0;r2<4;++r2) dv += dtin[sub][r2]*W_dt[r2*128 + c];
  dv = fmaxf(dv, 0.f) + log1pf(expf(-fabsf(dv)));   // softplus, stable
  dtarr[(size_t)token*128 + c] = dv;
}

// ---------------------------------------------------------------------------
// K5: selective scan. wave = (b,d), lane = s. Batch 8 recurrence steps, then
// 8 independent wave reductions (ILP hides shuffle latency).
__global__ __launch_bounds__(256) void k_scan(
    const float* __restrict__ dtarr, const float* __restrict__ uarr,
    const float* __restrict__ Bmp, const float* __restrict__ Cmp,
    const float* __restrict__ zsarr, const float* __restrict__ A_log,
    const float* __restrict__ Dm, float* __restrict__ ymp){
  int lane = threadIdx.x & 63, warp = threadIdx.x >> 6;
  int g = blockIdx.x*4 + warp;          // 0..1023
  int b = g >> 7, d = g & 127;
  float A = -expf(A_log[d*64 + lane]);
  float Dv = Dm[d];
  const float* dtp = dtarr + (size_t)b*1024*128 + d;
  const float* up  = uarr  + (size_t)b*1024*128 + d;
  const float* zp  = zsarr + (size_t)b*1024*128 + d;
  const float* Bp  = Bmp   + (size_t)b*1024*64 + lane;
  const float* Cp  = Cmp   + (size_t)b*1024*64 + lane;
  float* yp        = ymp   + (size_t)b*1024*128 + d;
  float h = 0.f;
  for(int t0=0; t0<1024; t0+=8){
    float dtc[8], uc[8], Bc[8], Cc[8], zc[8];
#pragma unroll
    for(int r=0;r<8;++r){
      dtc[r]=dtp[(size_t)(t0+r)*128]; uc[r]=up[(size_t)(t0+r)*128];
      Bc[r]=Bp[(size_t)(t0+r)*64];    Cc[r]=Cp[(size_t)(t0+r)*64];
      zc[r]=zp[(size_t)(t0+r)*128];
    }
    float hc[8];
#pragma unroll
    for(int r=0;r<8;++r){
      float dt = dtc[r];
      h = h*__expf(dt*A) + dt*uc[r]*Bc[r];
      hc[r] = h*Cc[r];
    }
    float y[8];
#pragma unroll
    for(int r=0;r<8;++r) y[r] = wsum64(hc[r]);
    if (lane==0){
#pragma unroll
      for(int r=0;r<8;++r) yp[(size_t)(t0+r)*128] = (y[r] + uc[r]*Dv)*zc[r];
    }
  }
}

// ---------------------------------------------------------------------------
// K6: y @ W_out + leaky + group(4)-RMS-norm. wave per token.
__global__ __launch_bounds__(256) void k_wout(
    const float* __restrict__ ymp, const float* __restrict__ W_out,
    const float* __restrict__ gamma, float* __restrict__ marr){
  int lane = threadIdx.x & 63, warp = threadIdx.x >> 6;
  int token = blockIdx.x*4 + warp;
  __shared__ float ys[4][128];
  ys[warp][lane]      = ymp[(size_t)token*128 + lane];
  ys[warp][lane+64]   = ymp[(size_t)token*128 + 64 + lane];
  __syncthreads();
  float acc = 0.f;
#pragma unroll 4
  for(int dd=0; dd<128; ++dd) acc += ys[warp][dd]*W_out[dd*64 + lane];
  acc = acc >= 0.f ? acc : 0.01f*acc;                 // leaky relu
  float ss = acc*acc;
#pragma unroll
  for(int m=1;m<16;m<<=1) ss += __shfl_xor(ss, m, 64); // 16-lane group sum
  float rms = sqrtf(ss)*0.25f;                         // * dpg^-0.5 (dpg=16)
  marr[(size_t)token*64 + lane] = acc/(rms + 1e-5f)*gamma[lane];
}

// ---------------------------------------------------------------------------
// K7: GLU conv1 -> h2[b, tau(0..1026), i(0..255)], tau-major. Weights read
// from c1wT (lane-contiguous dwords).
__global__ __launch_bounds__(256) void k_h2(
    const float* __restrict__ marr, const float* __restrict__ c1wT,
    const float* __restrict__ c1b, float* __restrict__ h2){
  int b = blockIdx.y;
  int t0 = blockIdx.x * 16;
  int tid = threadIdx.x;
  __shared__ float ms[19][64];
  for(int l = tid; l < 19*64; l += 256){
    int row = l >> 6, cc = l & 63;
    int t = t0 - 3 + row;
    ms[row][cc] = (t >= 0 && t < 1024) ? marr[((size_t)b*1024 + t)*64 + cc] : 0.f;
  }
  __syncthreads();
  int i = tid;
  float acc1[16], acc2[16];
#pragma unroll
  for(int tl=0;tl<16;++tl){ acc1[tl]=0.f; acc2[tl]=0.f; }
  for(int cc=0; cc<64; ++cc){
    float mv[19];
#pragma unroll
    for(int r2=0;r2<19;++r2) mv[r2] = ms[r2][cc];
    const float* wr = c1wT + (size_t)cc*4*512;
    float wa0 = wr[      i], wa1 = wr[ 512+i], wa2 = wr[1024+i], wa3 = wr[1536+i];
    float wg0 = wr[  256+i], wg1 = wr[ 768+i], wg2 = wr[1280+i], wg3 = wr[1792+i];
#pragma unroll
    for(int tl=0; tl<16; ++tl){
      acc1[tl] += wa0*mv[tl+0] + wa1*mv[tl+1] + wa2*mv[tl+2] + wa3*mv[tl+3];
      acc2[tl] += wg0*mv[tl+0] + wg1*mv[tl+1] + wg2*mv[tl+2] + wg3*mv[tl+3];
    }
  }
  float bb1 = c1b[i], bb2 = c1b[i+256];
#pragma unroll
  for(int tl=0; tl<16; ++tl){
    int t = t0 + tl;
    if (t < 1027){
      float o1 = acc1[tl] + bb1;
      float o2 = acc2[tl] + bb2;
      h2[((size_t)b*1027 + t)*256 + i] = o1 * silu_f(o2);
    }
  }
}

// ---------------------------------------------------------------------------
// K8: conv2 (flipped d1_w) + 0.5*ff + residuals + LN3 -> out.
// 16 tokens per block: d1w streamed ONCE per block (256KB), traffic cut 4x.
__global__ __launch_bounds__(256) void k_ff_final(
    const float* __restrict__ h2, const float* __restrict__ d1w, const float* __restrict__ d1b,
    const float* __restrict__ x2, const float* __restrict__ marr,
    const float* __restrict__ ln3w, const float* __restrict__ ln3b,
    float* __restrict__ out){
  int b = blockIdx.y;
  int s0 = blockIdx.x * 16;      // grid.x = 64
  int tid = threadIdx.x;
  int o = tid & 63, sg = tid >> 6;
  __shared__ float hs[19][256];
  for(int l = tid; l < 19*256; l += 256){
    int row = l >> 8, cc = l & 255;
    hs[row][cc] = h2[((size_t)b*1027 + s0 + row)*256 + cc];
  }
  __syncthreads();
  int sl = sg*4;
  float acc0=0.f, acc1=0.f, acc2=0.f, acc3=0.f;
  const float4* wb = (const float4*)d1w + o;   // d1w[i][o][0..3], lane-contig
#pragma unroll 2
  for(int i2=0; i2<256; ++i2){
    float4 wv = wb[(size_t)i2*64];
    float h0=hs[sl+0][i2], h1=hs[sl+1][i2], h2v=hs[sl+2][i2], h3=hs[sl+3][i2];
    float h4=hs[sl+4][i2], h5=hs[sl+5][i2], h6=hs[sl+6][i2];
    acc0 += h0*wv.w + h1*wv.z + h2v*wv.y + h3*wv.x;
    acc1 += h1*wv.w + h2v*wv.z + h3*wv.y + h4*wv.x;
    acc2 += h2v*wv.w + h3*wv.z + h4*wv.y + h5*wv.x;
    acc3 += h3*wv.w + h4*wv.z + h5*wv.y + h6*wv.x;
  }
  float accs[4] = {acc0, acc1, acc2, acc3};
  float bo_ = d1b[o];
#pragma unroll
  for(int r=0;r<4;++r){
    int s = s0 + sl + r;
    size_t idx = ((size_t)b*1024 + s)*64 + o;
    float tot = x2[idx] + marr[idx] + 0.5f*(accs[r] + bo_);
    float mean = wsum64(tot)*0.015625f;
    float dlt = tot - mean;
    float var = wsum64(dlt*dlt)*0.015625f;
    out[idx] = dlt*rsqrtf(var+1e-5f)*ln3w[o] + ln3b[o];
  }
}

// ---------------------------------------------------------------------------
extern "C" void kernel_launch(void* const* d_in, const int* in_sizes, int n_in,
                              void* d_out, int out_size, void* d_ws, size_t ws_size,
                              hipStream_t stream){
  const float* x       = (const float*)d_in[0];
  const int*   dmask   = (const int*)  d_in[1];   // bool -> int32 per harness
  const float* ln1w    = (const float*)d_in[2];
  const float* ln1b    = (const float*)d_in[3];
  const float* Wq      = (const float*)d_in[4];
  const float* Wkv     = (const float*)d_in[5];
  const float* Wo      = (const float*)d_in[6];
  const float* bo      = (const float*)d_in[7];
  const float* rel     = (const float*)d_in[8];
  const float* ln2w    = (const float*)d_in[9];
  const float* ln2b    = (const float*)d_in[10];
  const float* W_in    = (const float*)d_in[11];
  const float* conv_w  = (const float*)d_in[12];
  const float* conv_b  = (const float*)d_in[13];
  const float* W_xproj = (const float*)d_in[14];
  const float* W_dt    = (const float*)d_in[15];
  const float* b_dt    = (const float*)d_in[16];
  const float* A_log   = (const float*)d_in[17];
  const float* Dm      = (const float*)d_in[18];
  const float* W_out   = (const float*)d_in[19];
  const float* gamma   = (const float*)d_in[20];
  const float* c1w     = (const float*)d_in[21];
  const float* c1b     = (const float*)d_in[22];
  const float* d1w     = (const float*)d_in[23];
  const float* d1b     = (const float*)d_in[24];
  const float* ln3w    = (const float*)d_in[25];
  const float* ln3b    = (const float*)d_in[26];
  float* outp = (float*)d_out;

  float* ws = (float*)d_ws;
  float* qb       = ws;              // 524288
  float* kbT      = qb      + 524288;
  float* vbT      = kbT     + 524288;
  float* attn_raw = vbT     + 524288;
  float* x2       = attn_raw+ 524288;
  float* u0       = x2      + 524288;   // 1048576
  float* zsarr    = u0      + 1048576;
  float* uarr     = zsarr   + 1048576;
  float* dtarr    = uarr    + 1048576;
  float* Bmp      = dtarr   + 1048576;  // 524288
  float* Cmp      = Bmp     + 524288;
  float* ymp      = Cmp     + 524288;   // 1048576
  float* marr     = ymp     + 1048576;  // 524288
  float* h2       = marr    + 524288;   // 8*1027*256 = 2103296
  float* relT     = h2      + 2103296;  // 16*1025 = 16400
  float* c1wT     = relT    + 16400;    // 512*64*4 = 131072

  k_relT     <<<65, 256, 0, stream>>>(rel, relT);
  k_c1wT     <<<512, 256, 0, stream>>>(c1w, c1wT);
  k_ln1_qkv  <<<2048, 256, 0, stream>>>(x, ln1w, ln1b, Wq, Wkv, qb, kbT, vbT);
  k_attn     <<<dim3(128,32), 256, 0, stream>>>(qb, kbT, vbT, dmask, relT, attn_raw);
  k_post_attn<<<2048, 256, 0, stream>>>(x, attn_raw, Wo, bo, ln2w, ln2b, W_in, x2, u0, zsarr);
  k_conv_proj<<<4096, 256, 0, stream>>>(u0, conv_w, conv_b, W_xproj, W_dt, b_dt, uarr, Bmp, Cmp, dtarr);
  k_scan     <<<256, 256, 0, stream>>>(dtarr, uarr, Bmp, Cmp, zsarr, A_log, Dm, ymp);
  k_wout     <<<2048, 256, 0, stream>>>(ymp, W_out, gamma, marr);
  k_h2       <<<dim3(65,8), 256, 0, stream>>>(marr, c1wT, c1b, h2);
  k_ff_final <<<dim3(64,8), 256, 0, stream>>>(h2, d1w, d1b, x2, marr, ln3w, ln3b, outp);
}

// Round 8
// 808.127 us; speedup vs baseline: 1.2606x; 1.0063x over previous
//
#include <hip/hip_runtime.h>
#include <math.h>

// Shapes: B=8, N=1024, D=64, H=4, DH=16, DI=128, DS=64, DTR=4, MAXP=512

__device__ __forceinline__ float wsum64(float v){
#pragma unroll
  for(int m=32;m>0;m>>=1) v += __shfl_xor(v, m, 64);
  return v;
}
__device__ __forceinline__ float wmax64(float v){
#pragma unroll
  for(int m=32;m>0;m>>=1) v = fmaxf(v, __shfl_xor(v, m, 64));
  return v;
}
__device__ __forceinline__ float silu_f(float x){ return x / (1.f + __expf(-x)); }
__device__ __forceinline__ int clip512(int d){ return d < -512 ? -512 : (d > 512 ? 512 : d); }

// ---------------------------------------------------------------------------
// K1: LN1 + Q / KV projection (wave per token; K,V packed float2, D-major).
// ALSO fused: relT transpose (blocks 0..64) and c1wT transpose (blocks 65..576)
// -- independent prep work, saves 2 launches.
__global__ __launch_bounds__(256) void k_ln1_qkv(
    const float* __restrict__ x, const float* __restrict__ w1, const float* __restrict__ b1,
    const float* __restrict__ Wq, const float* __restrict__ Wkv,
    const float* __restrict__ rel, const float* __restrict__ c1w,
    float* __restrict__ qb, float2* __restrict__ kvT,
    float* __restrict__ relT, float* __restrict__ c1wT){
  int lane = threadIdx.x & 63, warp = threadIdx.x >> 6;
  int token = blockIdx.x*4 + warp;            // 0..8191
  __shared__ float xt[4][64];
  float xv = x[(size_t)token*64 + lane];
  float mean = wsum64(xv) * 0.015625f;
  float dlt = xv - mean;
  float var = wsum64(dlt*dlt) * 0.015625f;
  float xn = dlt * rsqrtf(var + 1e-5f) * w1[lane] + b1[lane];
  xt[warp][lane] = xn;
  __syncthreads();
  float aq=0.f, ak=0.f, av=0.f;
#pragma unroll 4
  for(int dd=0; dd<64; ++dd){
    float xd = xt[warp][dd];
    aq += xd * Wq[dd*64 + lane];
    ak += xd * Wkv[dd*128 + lane];
    av += xd * Wkv[dd*128 + 64 + lane];
  }
  int b = token >> 10, i = token & 1023;
  int h = lane >> 4, dh = lane & 15;
  size_t o  = (((size_t)(b*4 + h))*1024 + i)*16 + dh;   // (B,H,N,DH) for q
  size_t oT = (((size_t)(b*4 + h))*16 + dh)*1024 + i;   // (B,H,DH,N) for k,v
  qb[o]=aq;
  kvT[oT] = make_float2(ak, av);

  // fused prep transposes (independent of the work above)
  if (blockIdx.x < 65){
    int idx = blockIdx.x*256 + threadIdx.x;   // over 16*1025
    if (idx < 16*1025){
      int c = idx / 1025;
      int d = idx - c*1025;
      relT[idx] = rel[d*16 + c];
    }
  } else if (blockIdx.x < 577){
    int idx = (blockIdx.x-65)*256 + threadIdx.x;   // over 512*64*4 = 131072
    int row = idx >> 9;          // cc*4+k
    int ii  = idx & 511;
    c1wT[idx] = c1w[(size_t)ii*256 + row];
  }
}

// ---------------------------------------------------------------------------
// K2: attention. Block = 4 waves = 8 query rows (2 rows/wave). Gc[8][1024]
// (q_r . rel[dist]) precomputed ONCE per block -> barrier-free main loop.
// K/V packed float2 (one dwordx2 per c). Epilogue red[] aliases the Gc LDS.
__global__ __launch_bounds__(256, 3) void k_attn(
    const float* __restrict__ qb, const float2* __restrict__ kvT,
    const int* __restrict__ dmask, const float* __restrict__ relT,
    float* __restrict__ attn_raw){
  int tid = threadIdx.x;
  int lane = tid & 63, wv = tid >> 6;       // wave 0..3
  int bh  = blockIdx.y;                     // 0..31
  int i0  = blockIdx.x*8;                   // grid.x = 128
  int b = bh >> 2, h = bh & 3;
  int r0 = wv*2, r1 = wv*2 + 1;
  int i_a = i0 + r0, i_b = i0 + r1;

  __shared__ float Gc[8][1024];      // 32 KB; reused as red[] in epilogue
  __shared__ float qs[8][16];
  __shared__ float sums[8];

  if (tid < 128){
    int r = tid >> 4, c = tid & 15;
    qs[r][c] = qb[((size_t)bh*1024 + i0 + r)*16 + c] * 0.25f;
  }
  __syncthreads();

  // --- precompute Gc[r][j] = q_r . rel[clip(i0+r-j)] (32 entries/thread) ---
  {
    int r = tid >> 5, jb = tid & 31;
#pragma unroll 1
    for(int k=0;k<32;++k){
      int j = jb + 32*k;
      int d = clip512(i0 + r - j) + 512;
      float g = 0.f;
#pragma unroll
      for(int c=0;c<16;++c) g += qs[r][c]*relT[c*1025 + d];
      Gc[r][j] = g;
    }
  }
  float q0[16], q1[16];
#pragma unroll
  for(int c=0;c<16;++c){ q0[c]=qs[r0][c]; q1[c]=qs[r1][c]; }
  __syncthreads();

  const float2* kvb = kvT + (size_t)bh*16*1024;
  const int* mb0 = dmask + ((size_t)bh*1024 + i_a)*1024;
  const int* mb1 = dmask + ((size_t)bh*1024 + i_b)*1024;

  float m0=-3.0e38f, m1=-3.0e38f, s0=0.f, s1=0.f;
  float a0[16], a1[16];
#pragma unroll
  for(int c=0;c<16;++c){ a0[c]=0.f; a1[c]=0.f; }

#pragma unroll 1
  for(int t=0;t<16;++t){
    int j = lane + 64*t;
    int mk0 = mb0[j], mk1 = mb1[j];
    float2 kv[16];
#pragma unroll
    for(int c=0;c<16;++c) kv[c] = kvb[c*1024 + j];
    float sv0 = Gc[r0][j] + (mk0 ? -1.0e12f : 0.0f);
    float sv1 = Gc[r1][j] + (mk1 ? -1.0e12f : 0.0f);
#pragma unroll
    for(int c=0;c<16;++c){ sv0 += q0[c]*kv[c].x; sv1 += q1[c]*kv[c].x; }
    float mn0 = fmaxf(m0, sv0);
    float al0 = __expf(m0 - mn0);
    float p0  = __expf(sv0 - mn0);
    m0 = mn0; s0 = s0*al0 + p0;
#pragma unroll
    for(int c=0;c<16;++c) a0[c] = a0[c]*al0 + p0*kv[c].y;
    float mn1 = fmaxf(m1, sv1);
    float al1 = __expf(m1 - mn1);
    float p1  = __expf(sv1 - mn1);
    m1 = mn1; s1 = s1*al1 + p1;
#pragma unroll
    for(int c=0;c<16;++c) a1[c] = a1[c]*al1 + p1*kv[c].y;
  }
  // merge lanes per row
  float M0 = wmax64(m0), M1 = wmax64(m1);
  float sc0 = __expf(m0 - M0), sc1 = __expf(m1 - M1);
  s0 = wsum64(s0*sc0); s1 = wsum64(s1*sc1);
#pragma unroll
  for(int c=0;c<16;++c){
    float x0 = a0[c]*sc0;
    x0 += __shfl_xor(x0, 32, 64); x0 += __shfl_xor(x0, 16, 64);
    a0[c] = x0;
    float x1 = a1[c]*sc1;
    x1 += __shfl_xor(x1, 32, 64); x1 += __shfl_xor(x1, 16, 64);
    a1[c] = x1;
  }
  __syncthreads();            // all waves done reading Gc -> safe to alias
  float* red = &Gc[0][0];     // red[row][g][c] : row*272 + g*17 + c (8704 B)
  if (lane < 16){
#pragma unroll
    for(int c=0;c<16;++c){
      red[r0*272 + lane*17 + c] = a0[c];
      red[r1*272 + lane*17 + c] = a1[c];
    }
  }
  if (lane == 0){ sums[r0] = s0; sums[r1] = s1; }
  __syncthreads();
  if (tid < 128){
    int row = tid >> 4, c = tid & 15;
    float tot = 0.f;
#pragma unroll
    for(int g=0; g<16; ++g) tot += red[row*272 + g*17 + c];
    int irow = i0 + row;
    attn_raw[((size_t)b*1024 + irow)*64 + h*16 + c] = tot / sums[row];
  }
}

// ---------------------------------------------------------------------------
// K3: Wo proj + double residual + LN2 + W_in (u0, silu(z)). wave per token.
__global__ __launch_bounds__(256) void k_post_attn(
    const float* __restrict__ x, const float* __restrict__ attn_raw,
    const float* __restrict__ Wo, const float* __restrict__ bo,
    const float* __restrict__ ln2w, const float* __restrict__ ln2b,
    const float* __restrict__ W_in,
    float* __restrict__ x2, float* __restrict__ u0, float* __restrict__ zsarr){
  int lane = threadIdx.x & 63, warp = threadIdx.x >> 6;
  int token = blockIdx.x*4 + warp;
  __shared__ float ar[4][64];
  __shared__ float lnv[4][64];
  ar[warp][lane] = attn_raw[(size_t)token*64 + lane];
  __syncthreads();
  float acc = bo[lane];
#pragma unroll 4
  for(int dd=0;dd<64;++dd) acc += ar[warp][dd]*Wo[dd*64+lane];
  float t = 2.f*x[(size_t)token*64+lane] + acc;    // x + (attn_out + x)
  x2[(size_t)token*64+lane] = t;
  float mean = wsum64(t)*0.015625f;
  float dlt = t-mean;
  float var = wsum64(dlt*dlt)*0.015625f;
  float ln = dlt*rsqrtf(var+1e-5f)*ln2w[lane]+ln2b[lane];
  lnv[warp][lane]=ln;
  __syncthreads();
  float a0=0.f,a1=0.f,a2=0.f,a3=0.f;
#pragma unroll 4
  for(int dd=0;dd<64;++dd){
    float xd = lnv[warp][dd];
    const float* wr = W_in + dd*256;
    a0 += xd*wr[lane]; a1 += xd*wr[lane+64]; a2 += xd*wr[lane+128]; a3 += xd*wr[lane+192];
  }
  u0[(size_t)token*128 + lane] = a0;
  u0[(size_t)token*128 + 64 + lane] = a1;
  zsarr[(size_t)token*128 + lane] = silu_f(a2);
  zsarr[(size_t)token*128 + 64 + lane] = silu_f(a3);
}

// ---------------------------------------------------------------------------
// K4: causal depthwise conv4 + silu + x-proj(132) + softplus dt. 128 lanes/token.
__global__ __launch_bounds__(256) void k_conv_proj(
    const float* __restrict__ u0, const float* __restrict__ conv_w, const float* __restrict__ conv_b,
    const float* __restrict__ W_xproj, const float* __restrict__ W_dt, const float* __restrict__ b_dt,
    float* __restrict__ uarr, float* __restrict__ Bmp, float* __restrict__ Cmp, float* __restrict__ dtarr){
  int sub = threadIdx.x >> 7, c = threadIdx.x & 127;
  int token = blockIdx.x*2 + sub;
  int b = token >> 10, i = token & 1023;
  __shared__ float us[2][128];
  __shared__ float dtin[2][4];
  float acc = conv_b[c];
#pragma unroll
  for(int k2=0;k2<4;++k2){
    int t2 = i - 3 + k2;
    if (t2 >= 0) acc += u0[((size_t)b*1024 + t2)*128 + c]*conv_w[c*4+k2];
  }
  float uv = silu_f(acc);
  uarr[(size_t)token*128 + c] = uv;
  us[sub][c] = uv;
  __syncthreads();
  float accA = 0.f, accB = 0.f;
  int cB = 128 + (c & 3);
#pragma unroll 4
  for(int dd=0; dd<128; ++dd){
    float xd = us[sub][dd];
    accA += xd * W_xproj[dd*132 + c];
    accB += xd * W_xproj[dd*132 + cB];
  }
  if (c < 4){ dtin[sub][c] = accA; Cmp[(size_t)token*64 + 60 + c] = accB; }
  else if (c < 68) Bmp[(size_t)token*64 + (c-4)] = accA;
  else             Cmp[(size_t)token*64 + (c-68)] = accA;
  __syncthreads();
  float dv = b_dt[c];
#pragma unroll
  for(int r2=0;r2<4;++r2) dv += dtin[sub][r2]*W_dt[r2*128 + c];
  dv = fmaxf(dv, 0.f) + log1pf(expf(-fabsf(dv)));   // softplus, stable
  dtarr[(size_t)token*128 + c] = dv;
}

// ---------------------------------------------------------------------------
// K5: selective scan. wave = (b,d), lane = s. Batch 8 recurrence steps, then
// 8 independent wave reductions (ILP hides shuffle latency).
__global__ __launch_bounds__(256) void k_scan(
    const float* __restrict__ dtarr, const float* __restrict__ uarr,
    const float* __restrict__ Bmp, const float* __restrict__ Cmp,
    const float* __restrict__ zsarr, const float* __restrict__ A_log,
    const float* __restrict__ Dm, float* __restrict__ ymp){
  int lane = threadIdx.x & 63, warp = threadIdx.x >> 6;
  int g = blockIdx.x*4 + warp;          // 0..1023
  int b = g >> 7, d = g & 127;
  float A = -expf(A_log[d*64 + lane]);
  float Dv = Dm[d];
  const float* dtp = dtarr + (size_t)b*1024*128 + d;
  const float* up  = uarr  + (size_t)b*1024*128 + d;
  const float* zp  = zsarr + (size_t)b*1024*128 + d;
  const float* Bp  = Bmp   + (size_t)b*1024*64 + lane;
  const float* Cp  = Cmp   + (size_t)b*1024*64 + lane;
  float* yp        = ymp   + (size_t)b*1024*128 + d;
  float h = 0.f;
  for(int t0=0; t0<1024; t0+=8){
    float dtc[8], uc[8], Bc[8], Cc[8], zc[8];
#pragma unroll
    for(int r=0;r<8;++r){
      dtc[r]=dtp[(size_t)(t0+r)*128]; uc[r]=up[(size_t)(t0+r)*128];
      Bc[r]=Bp[(size_t)(t0+r)*64];    Cc[r]=Cp[(size_t)(t0+r)*64];
      zc[r]=zp[(size_t)(t0+r)*128];
    }
    float hc[8];
#pragma unroll
    for(int r=0;r<8;++r){
      float dt = dtc[r];
      h = h*__expf(dt*A) + dt*uc[r]*Bc[r];
      hc[r] = h*Cc[r];
    }
    float y[8];
#pragma unroll
    for(int r=0;r<8;++r) y[r] = wsum64(hc[r]);
    if (lane==0){
#pragma unroll
      for(int r=0;r<8;++r) yp[(size_t)(t0+r)*128] = (y[r] + uc[r]*Dv)*zc[r];
    }
  }
}

// ---------------------------------------------------------------------------
// K6: y @ W_out + leaky + group(4)-RMS-norm. wave per token.
__global__ __launch_bounds__(256) void k_wout(
    const float* __restrict__ ymp, const float* __restrict__ W_out,
    const float* __restrict__ gamma, float* __restrict__ marr){
  int lane = threadIdx.x & 63, warp = threadIdx.x >> 6;
  int token = blockIdx.x*4 + warp;
  __shared__ float ys[4][128];
  ys[warp][lane]      = ymp[(size_t)token*128 + lane];
  ys[warp][lane+64]   = ymp[(size_t)token*128 + 64 + lane];
  __syncthreads();
  float acc = 0.f;
#pragma unroll 4
  for(int dd=0; dd<128; ++dd) acc += ys[warp][dd]*W_out[dd*64 + lane];
  acc = acc >= 0.f ? acc : 0.01f*acc;                 // leaky relu
  float ss = acc*acc;
#pragma unroll
  for(int m=1;m<16;m<<=1) ss += __shfl_xor(ss, m, 64); // 16-lane group sum
  float rms = sqrtf(ss)*0.25f;                         // * dpg^-0.5 (dpg=16)
  marr[(size_t)token*64 + lane] = acc/(rms + 1e-5f)*gamma[lane];
}

// ---------------------------------------------------------------------------
// K7: GLU conv1 -> h2[b, tau(0..1026), i(0..255)], tau-major. Weights read
// from c1wT (lane-contiguous dwords).
__global__ __launch_bounds__(256) void k_h2(
    const float* __restrict__ marr, const float* __restrict__ c1wT,
    const float* __restrict__ c1b, float* __restrict__ h2){
  int b = blockIdx.y;
  int t0 = blockIdx.x * 16;
  int tid = threadIdx.x;
  __shared__ float ms[19][64];
  for(int l = tid; l < 19*64; l += 256){
    int row = l >> 6, cc = l & 63;
    int t = t0 - 3 + row;
    ms[row][cc] = (t >= 0 && t < 1024) ? marr[((size_t)b*1024 + t)*64 + cc] : 0.f;
  }
  __syncthreads();
  int i = tid;
  float acc1[16], acc2[16];
#pragma unroll
  for(int tl=0;tl<16;++tl){ acc1[tl]=0.f; acc2[tl]=0.f; }
  for(int cc=0; cc<64; ++cc){
    float mv[19];
#pragma unroll
    for(int r2=0;r2<19;++r2) mv[r2] = ms[r2][cc];
    const float* wr = c1wT + (size_t)cc*4*512;
    float wa0 = wr[      i], wa1 = wr[ 512+i], wa2 = wr[1024+i], wa3 = wr[1536+i];
    float wg0 = wr[  256+i], wg1 = wr[ 768+i], wg2 = wr[1280+i], wg3 = wr[1792+i];
#pragma unroll
    for(int tl=0; tl<16; ++tl){
      acc1[tl] += wa0*mv[tl+0] + wa1*mv[tl+1] + wa2*mv[tl+2] + wa3*mv[tl+3];
      acc2[tl] += wg0*mv[tl+0] + wg1*mv[tl+1] + wg2*mv[tl+2] + wg3*mv[tl+3];
    }
  }
  float bb1 = c1b[i], bb2 = c1b[i+256];
#pragma unroll
  for(int tl=0; tl<16; ++tl){
    int t = t0 + tl;
    if (t < 1027){
      float o1 = acc1[tl] + bb1;
      float o2 = acc2[tl] + bb2;
      h2[((size_t)b*1027 + t)*256 + i] = o1 * silu_f(o2);
    }
  }
}

// ---------------------------------------------------------------------------
// K8: conv2 (flipped d1_w) + 0.5*ff + residuals + LN3 -> out.
// 16 tokens per block: d1w streamed ONCE per block (256KB).
__global__ __launch_bounds__(256) void k_ff_final(
    const float* __restrict__ h2, const float* __restrict__ d1w, const float* __restrict__ d1b,
    const float* __restrict__ x2, const float* __restrict__ marr,
    const float* __restrict__ ln3w, const float* __restrict__ ln3b,
    float* __restrict__ out){
  int b = blockIdx.y;
  int s0 = blockIdx.x * 16;      // grid.x = 64
  int tid = threadIdx.x;
  int o = tid & 63, sg = tid >> 6;
  __shared__ float hs[19][256];
  for(int l = tid; l < 19*256; l += 256){
    int row = l >> 8, cc = l & 255;
    hs[row][cc] = h2[((size_t)b*1027 + s0 + row)*256 + cc];
  }
  __syncthreads();
  int sl = sg*4;
  float acc0=0.f, acc1=0.f, acc2=0.f, acc3=0.f;
  const float4* wb = (const float4*)d1w + o;   // d1w[i][o][0..3], lane-contig
#pragma unroll 2
  for(int i2=0; i2<256; ++i2){
    float4 wv = wb[(size_t)i2*64];
    float h0=hs[sl+0][i2], h1=hs[sl+1][i2], h2v=hs[sl+2][i2], h3=hs[sl+3][i2];
    float h4=hs[sl+4][i2], h5=hs[sl+5][i2], h6=hs[sl+6][i2];
    acc0 += h0*wv.w + h1*wv.z + h2v*wv.y + h3*wv.x;
    acc1 += h1*wv.w + h2v*wv.z + h3*wv.y + h4*wv.x;
    acc2 += h2v*wv.w + h3*wv.z + h4*wv.y + h5*wv.x;
    acc3 += h3*wv.w + h4*wv.z + h5*wv.y + h6*wv.x;
  }
  float accs[4] = {acc0, acc1, acc2, acc3};
  float bo_ = d1b[o];
#pragma unroll
  for(int r=0;r<4;++r){
    int s = s0 + sl + r;
    size_t idx = ((size_t)b*1024 + s)*64 + o;
    float tot = x2[idx] + marr[idx] + 0.5f*(accs[r] + bo_);
    float mean = wsum64(tot)*0.015625f;
    float dlt = tot - mean;
    float var = wsum64(dlt*dlt)*0.015625f;
    out[idx] = dlt*rsqrtf(var+1e-5f)*ln3w[o] + ln3b[o];
  }
}

// ---------------------------------------------------------------------------
extern "C" void kernel_launch(void* const* d_in, const int* in_sizes, int n_in,
                              void* d_out, int out_size, void* d_ws, size_t ws_size,
                              hipStream_t stream){
  const float* x       = (const float*)d_in[0];
  const int*   dmask   = (const int*)  d_in[1];   // bool -> int32 per harness
  const float* ln1w    = (const float*)d_in[2];
  const float* ln1b    = (const float*)d_in[3];
  const float* Wq      = (const float*)d_in[4];
  const float* Wkv     = (const float*)d_in[5];
  const float* Wo      = (const float*)d_in[6];
  const float* bo      = (const float*)d_in[7];
  const float* rel     = (const float*)d_in[8];
  const float* ln2w    = (const float*)d_in[9];
  const float* ln2b    = (const float*)d_in[10];
  const float* W_in    = (const float*)d_in[11];
  const float* conv_w  = (const float*)d_in[12];
  const float* conv_b  = (const float*)d_in[13];
  const float* W_xproj = (const float*)d_in[14];
  const float* W_dt    = (const float*)d_in[15];
  const float* b_dt    = (const float*)d_in[16];
  const float* A_log   = (const float*)d_in[17];
  const float* Dm      = (const float*)d_in[18];
  const float* W_out   = (const float*)d_in[19];
  const float* gamma   = (const float*)d_in[20];
  const float* c1w     = (const float*)d_in[21];
  const float* c1b     = (const float*)d_in[22];
  const float* d1w     = (const float*)d_in[23];
  const float* d1b     = (const float*)d_in[24];
  const float* ln3w    = (const float*)d_in[25];
  const float* ln3b    = (const float*)d_in[26];
  float* outp = (float*)d_out;

  float* ws = (float*)d_ws;
  float* qb       = ws;              // 524288
  float* kvT      = qb      + 524288;   // 1048576 (float2 x 524288)
  float* attn_raw = kvT     + 1048576;  // 524288
  float* x2       = attn_raw+ 524288;
  float* u0       = x2      + 524288;   // 1048576
  float* zsarr    = u0      + 1048576;
  float* uarr     = zsarr   + 1048576;
  float* dtarr    = uarr    + 1048576;
  float* Bmp      = dtarr   + 1048576;  // 524288
  float* Cmp      = Bmp     + 524288;
  float* ymp      = Cmp     + 524288;   // 1048576
  float* marr     = ymp     + 1048576;  // 524288
  float* h2       = marr    + 524288;   // 8*1027*256 = 2103296
  float* relT     = h2      + 2103296;  // 16*1025 = 16400
  float* c1wT     = relT    + 16400;    // 512*64*4 = 131072

  k_ln1_qkv  <<<2048, 256, 0, stream>>>(x, ln1w, ln1b, Wq, Wkv, rel, c1w,
                                        qb, (float2*)kvT, relT, c1wT);
  k_attn     <<<dim3(128,32), 256, 0, stream>>>(qb, (const float2*)kvT, dmask, relT, attn_raw);
  k_post_attn<<<2048, 256, 0, stream>>>(x, attn_raw, Wo, bo, ln2w, ln2b, W_in, x2, u0, zsarr);
  k_conv_proj<<<4096, 256, 0, stream>>>(u0, conv_w, conv_b, W_xproj, W_dt, b_dt, uarr, Bmp, Cmp, dtarr);
  k_scan     <<<256, 256, 0, stream>>>(dtarr, uarr, Bmp, Cmp, zsarr, A_log, Dm, ymp);
  k_wout     <<<2048, 256, 0, stream>>>(ymp, W_out, gamma, marr);
  k_h2       <<<dim3(65,8), 256, 0, stream>>>(marr, c1wT, c1b, h2);
  k_ff_final <<<dim3(64,8), 256, 0, stream>>>(h2, d1w, d1b, x2, marr, ln3w, ln3b, outp);
}